// Round 9
// baseline (1415.193 us; speedup 1.0000x reference)
//
#include <hip/hip_runtime.h>
#include <hip/hip_bf16.h>
#include <math.h>

#define B_SZ 4
#define T_LEN 8192
#define C_IN 7
#define NPATCH 1023
#define DIM 512
#define NH 8
#define HD 64
#define NLAYERS 4
#define MLP_HID 2048
#define M_ROWS (B_SZ * NPATCH)   // 4092
#define KEMB 128                 // padded patch length (112 real + 16 zero)
#define LN_EPS 1e-5f

typedef __attribute__((ext_vector_type(8))) short short8;
typedef __attribute__((ext_vector_type(4))) float float4v;

static __device__ __forceinline__ unsigned short f2bf(float f) {
  __hip_bfloat16 h = __float2bfloat16(f);
  return *reinterpret_cast<unsigned short*>(&h);
}
static __device__ __forceinline__ float bf2f(unsigned short u) {
  return __uint_as_float(((unsigned)u) << 16);
}

// ---------------------------------------------------------------------------
// Patch gather: Pm[row][c*16+p] = bf16(x[b, i*8+p, c]); cols 112..127 = 0.
// ---------------------------------------------------------------------------
__global__ __launch_bounds__(256) void patch_kernel(
    const float* __restrict__ x, unsigned short* __restrict__ Pm) {
  int idx = blockIdx.x * 256 + threadIdx.x;
  if (idx >= M_ROWS * KEMB) return;
  int row = idx >> 7, c = idx & 127;
  float v = 0.f;
  if (c < 112) {
    int b = row / NPATCH, i = row - b * NPATCH;
    int ci = c >> 4, p = c & 15;
    v = x[((size_t)b * T_LEN + (size_t)i * 8 + p) * C_IN + ci];
  }
  Pm[idx] = f2bf(v);
}

// ---------------------------------------------------------------------------
// W_emb convert: Wt[n][k] = bf16(W_emb[k][n]) for k<112, 0 for k in [112,128).
// ---------------------------------------------------------------------------
__global__ __launch_bounds__(256) void wemb_cvt_kernel(
    const float* __restrict__ W, unsigned short* __restrict__ Wt) {
  int idx = blockIdx.x * 256 + threadIdx.x;
  if (idx >= DIM * KEMB) return;
  int n = idx >> 7, k = idx & 127;
  float v = (k < 112) ? W[(size_t)k * DIM + n] : 0.f;
  Wt[idx] = f2bf(v);
}

// ---------------------------------------------------------------------------
// LayerNorm, 4 rows/block. BF: bf16 vs fp32 out.
// ---------------------------------------------------------------------------
template <bool BF>
__global__ __launch_bounds__(256) void ln_kernel(
    const float* __restrict__ in, const float* __restrict__ g,
    const float* __restrict__ bb, void* __restrict__ outv, int M) {
  int row = blockIdx.x * 4 + (threadIdx.x >> 6);
  if (row >= M) return;
  int lane = threadIdx.x & 63;
  const float* xr = in + (size_t)row * DIM;
  float v[8];
  float s = 0.f;
  #pragma unroll
  for (int k = 0; k < 8; ++k) { v[k] = xr[lane + 64 * k]; s += v[k]; }
  #pragma unroll
  for (int off = 32; off; off >>= 1) s += __shfl_down(s, off);
  s = __shfl(s, 0);
  float mu = s * (1.f / DIM);
  float q = 0.f;
  #pragma unroll
  for (int k = 0; k < 8; ++k) { float d = v[k] - mu; q = fmaf(d, d, q); }
  #pragma unroll
  for (int off = 32; off; off >>= 1) q += __shfl_down(q, off);
  q = __shfl(q, 0);
  float rstd = rsqrtf(q * (1.f / DIM) + LN_EPS);
  #pragma unroll
  for (int k = 0; k < 8; ++k) {
    int d = lane + 64 * k;
    float r = (v[k] - mu) * rstd * g[d] + bb[d];
    if (BF)
      ((unsigned short*)outv)[(size_t)row * DIM + d] = f2bf(r);
    else
      ((float*)outv)[(size_t)row * DIM + d] = r;
  }
}

// ---------------------------------------------------------------------------
// Weight convert + transpose: W[K][N] fp32 -> Wt[N][K] bf16 (per layer z).
// ---------------------------------------------------------------------------
__global__ __launch_bounds__(256) void wcvt_kernel(
    const float* __restrict__ W, unsigned short* __restrict__ Wt, int K, int N) {
  __shared__ float tile[32][33];
  int n0 = blockIdx.x * 32, k0 = blockIdx.y * 32, L = blockIdx.z;
  const float* Ws = W + (size_t)L * K * N;
  unsigned short* Wd = Wt + (size_t)L * K * N;
  int tx = threadIdx.x & 31, ty = threadIdx.x >> 5;
  #pragma unroll
  for (int i = 0; i < 4; ++i)
    tile[ty + i * 8][tx] = Ws[(size_t)(k0 + ty + i * 8) * N + n0 + tx];
  __syncthreads();
  #pragma unroll
  for (int i = 0; i < 4; ++i)
    Wd[(size_t)(n0 + ty + i * 8) * K + k0 + tx] = f2bf(tile[tx][ty + i * 8]);
}

// ---------------------------------------------------------------------------
// RoPE cos/sin table: tab[i*32+j] = (cos, sin) of i * 10000^(-j/32).
// ---------------------------------------------------------------------------
__global__ __launch_bounds__(256) void rope_tab_kernel(float2* __restrict__ tab) {
  int idx = blockIdx.x * 256 + threadIdx.x;
  if (idx >= NPATCH * 32) return;
  int i = idx >> 5, j = idx & 31;
  float inv = powf(10000.0f, -(float)j * (1.0f / 32.0f));
  float sn, cs;
  sincosf((float)i * inv, &sn, &cs);
  tab[idx] = make_float2(cs, sn);
}

// ---------------------------------------------------------------------------
// bf16 MFMA GEMM, TM x 128 tile (TM = 32/64/128), BK=32, 4 waves, depth-2
// register prefetch (two K-tiles in flight).
// EPI: 1 = bias + res -> fp32 (res==Cf ok: h += ...);
//      2 = bias + GELU -> bf16; 3 = bias -> bf16;
//      5 = bias -> fp32 to BOTH Cf and Cf2 (embed);
//      6 = bias + RoPE (q scaled 1/8) -> bf16 (qkv; rtab used).
// ---------------------------------------------------------------------------
template <int TM, int EPI>
__global__ __launch_bounds__(256) void mfma_gemm(
    const unsigned short* __restrict__ A, const unsigned short* __restrict__ Bt,
    const float* __restrict__ bias, const float* __restrict__ res,
    float* __restrict__ Cf, float* __restrict__ Cf2,
    unsigned short* __restrict__ Cb, const float2* __restrict__ rtab,
    int M, int N, int K) {
  constexpr int NI = TM / 32;                 // M-frags per wave (TM=32 -> 1)
  constexpr int ALOADS = TM * 4;              // uint4 loads for A tile
  constexpr int CHN = (ALOADS + 255) / 256;   // A chunks per thread
  __shared__ __align__(16) unsigned short As[TM][40];
  __shared__ __align__(16) unsigned short Bs[128][40];
  const int bm = blockIdx.y * TM;
  const int bn = blockIdx.x * 128;
  const int tid = threadIdx.x;
  const int lane = tid & 63, wave = tid >> 6;
  const int quad = lane >> 4, l16 = lane & 15;
  const int wm = (wave & 1) * (TM / 2);
  const int wn = (wave >> 1) * 64;

  float4v acc[NI][4];
  #pragma unroll
  for (int i = 0; i < NI; ++i)
    #pragma unroll
    for (int j = 0; j < 4; ++j)
      acc[i][j] = (float4v){0.f, 0.f, 0.f, 0.f};

  uint4 pa[2][CHN], pb[2][2];
  auto load_tiles = [&](int kk, int buf) {
    #pragma unroll
    for (int it = 0; it < CHN; ++it) {
      int idx = tid + it * 256;
      if ((ALOADS & 255) == 0 || idx < ALOADS) {
        int row = idx >> 2, ch = (idx & 3) * 8;
        int gm = bm + row;
        pa[buf][it] = make_uint4(0u, 0u, 0u, 0u);
        if (gm < M) pa[buf][it] = *(const uint4*)(A + (size_t)gm * K + kk + ch);
      }
    }
    #pragma unroll
    for (int it = 0; it < 2; ++it) {
      int idx = tid + it * 256;
      int row = idx >> 2, ch = (idx & 3) * 8;
      pb[buf][it] = *(const uint4*)(Bt + (size_t)(bn + row) * K + kk + ch);
    }
  };

  load_tiles(0, 0);
  if (K > 32) load_tiles(32, 1);
  int cur = 0;
  for (int k0 = 0; k0 < K; k0 += 32) {
    #pragma unroll
    for (int it = 0; it < CHN; ++it) {
      int idx = tid + it * 256;
      if ((ALOADS & 255) == 0 || idx < ALOADS)
        *(uint4*)&As[idx >> 2][(idx & 3) * 8] = pa[cur][it];
    }
    #pragma unroll
    for (int it = 0; it < 2; ++it) {
      int idx = tid + it * 256;
      *(uint4*)&Bs[idx >> 2][(idx & 3) * 8] = pb[cur][it];
    }
    __syncthreads();
    if (k0 + 64 < K) load_tiles(k0 + 64, cur);   // depth-2 prefetch
    short8 af[NI], bfr[4];
    #pragma unroll
    for (int i = 0; i < NI; ++i)
      af[i] = *(const short8*)&As[wm + i * 16 + l16][quad * 8];
    #pragma unroll
    for (int j = 0; j < 4; ++j)
      bfr[j] = *(const short8*)&Bs[wn + j * 16 + l16][quad * 8];
    #pragma unroll
    for (int i = 0; i < NI; ++i)
      #pragma unroll
      for (int j = 0; j < 4; ++j)
        acc[i][j] = __builtin_amdgcn_mfma_f32_16x16x32_bf16(
            af[i], bfr[j], acc[i][j], 0, 0, 0);
    __syncthreads();
    cur ^= 1;
  }

  if (EPI == 6) {
    const int sec = (bn + wn) >> 9;   // 0=q, 1=k, 2=v (wave-uniform)
    #pragma unroll
    for (int i = 0; i < NI; ++i) {
      int gm0 = bm + wm + i * 16 + quad * 4;
      #pragma unroll
      for (int r = 0; r < 4; ++r) {
        int gm = gm0 + r;
        if (gm >= M) continue;
        size_t rowoff = (size_t)gm * N;
        if (sec < 2) {
          int ip = gm; if (ip >= 2046) ip -= 2046; if (ip >= 1023) ip -= 1023;
          float sc = (sec == 0) ? 0.125f : 1.f;
          #pragma unroll
          for (int j = 0; j < 2; ++j) {
            int gn = bn + wn + j * 16 + l16;
            float v0 = acc[i][j][r] + bias[gn];
            float v1 = acc[i][j + 2][r] + bias[gn + 32];
            float2 t = rtab[ip * 32 + j * 16 + l16];
            Cb[rowoff + gn]      = f2bf((v0 * t.x - v1 * t.y) * sc);
            Cb[rowoff + gn + 32] = f2bf((v1 * t.x + v0 * t.y) * sc);
          }
        } else {
          #pragma unroll
          for (int j = 0; j < 4; ++j) {
            int gn = bn + wn + j * 16 + l16;
            Cb[rowoff + gn] = f2bf(acc[i][j][r] + bias[gn]);
          }
        }
      }
    }
    return;
  }

  #pragma unroll
  for (int j = 0; j < 4; ++j) {
    int gn = bn + wn + j * 16 + l16;
    float bv = bias[gn];
    #pragma unroll
    for (int i = 0; i < NI; ++i) {
      int gm0 = bm + wm + i * 16 + quad * 4;
      #pragma unroll
      for (int r = 0; r < 4; ++r) {
        int gm = gm0 + r;
        if (gm < M) {
          float v = acc[i][j][r] + bv;
          size_t off = (size_t)gm * N + gn;
          if (EPI == 1) {
            Cf[off] = v + res[off];
          } else if (EPI == 2) {
            Cb[off] = f2bf(0.5f * v * (1.f + erff(v * 0.70710678118f)));
          } else if (EPI == 3) {
            Cb[off] = f2bf(v);
          } else {
            Cf[off] = v;
            Cf2[off] = v;
          }
        }
      }
    }
  }
}

// ---------------------------------------------------------------------------
// MFMA flash attention with depth-1 K/V register prefetch.
// Block = 4 waves = 64 queries.
// ---------------------------------------------------------------------------
#define APITCH 72

__global__ __launch_bounds__(256) void attn_kernel(
    const unsigned short* __restrict__ qkvb, unsigned short* __restrict__ o) {
  const int qt0 = blockIdx.x * 64;
  const int h = blockIdx.y;
  const int b = blockIdx.z;
  const int tid = threadIdx.x;
  const int lane = tid & 63, wave = tid >> 6;
  const int quad = lane >> 4, l16 = lane & 15;

  __shared__ __align__(16) unsigned short Qs[64][APITCH];
  __shared__ __align__(16) unsigned short Ks[64][APITCH];
  __shared__ __align__(16) unsigned short Vt[HD][APITCH];
  __shared__ __align__(16) unsigned short Ps[4][16][APITCH];

  const int sr = tid >> 2;             // staging row 0..63
  const int sc0 = (tid & 3) * 16;      // staging col 0,16,32,48

  {
    int qi = qt0 + sr;
    uint4 a = make_uint4(0u, 0u, 0u, 0u), b2 = a;
    if (qi < NPATCH) {
      const uint4* src = (const uint4*)(qkvb + (size_t)(b * NPATCH + qi) * (3 * DIM) + h * HD + sc0);
      a = src[0]; b2 = src[1];
    }
    *(uint4*)&Qs[sr][sc0] = a;
    *(uint4*)&Qs[sr][sc0 + 8] = b2;
  }

  uint4 pk0, pk1, pv0, pv1;
  auto load_kv = [&](int j0) {
    int j = j0 + sr;
    pk0 = pk1 = pv0 = pv1 = make_uint4(0u, 0u, 0u, 0u);
    if (j < NPATCH) {
      const unsigned short* baseb = qkvb + (size_t)(b * NPATCH + j) * (3 * DIM) + h * HD;
      pk0 = *(const uint4*)(baseb + DIM + sc0);
      pk1 = *(const uint4*)(baseb + DIM + sc0 + 8);
      pv0 = *(const uint4*)(baseb + 2 * DIM + sc0);
      pv1 = *(const uint4*)(baseb + 2 * DIM + sc0 + 8);
    }
  };
  load_kv(0);
  __syncthreads();

  short8 aq0 = *(const short8*)&Qs[wave * 16 + l16][quad * 8];
  short8 aq1 = *(const short8*)&Qs[wave * 16 + l16][32 + quad * 8];

  float4v accO[4];
  #pragma unroll
  for (int j2 = 0; j2 < 4; ++j2) accO[j2] = (float4v){0.f, 0.f, 0.f, 0.f};
  float m_run[4] = {-1e30f, -1e30f, -1e30f, -1e30f};
  float l_run[4] = {0.f, 0.f, 0.f, 0.f};

  for (int j0 = 0; j0 < NPATCH; j0 += 64) {
    // ---- write prefetched K/V tile to LDS ----
    {
      *(uint4*)&Ks[sr][sc0] = pk0;
      *(uint4*)&Ks[sr][sc0 + 8] = pk1;
      unsigned short vs[16];
      *(uint4*)&vs[0] = pv0;
      *(uint4*)&vs[8] = pv1;
      #pragma unroll
      for (int u = 0; u < 16; ++u) Vt[sc0 + u][sr] = vs[u];
    }
    __syncthreads();
    if (j0 + 64 < NPATCH) load_kv(j0 + 64);   // prefetch next tile

    float4v s[4];
    #pragma unroll
    for (int j = 0; j < 4; ++j) {
      s[j] = (float4v){0.f, 0.f, 0.f, 0.f};
      short8 bk0 = *(const short8*)&Ks[j * 16 + l16][quad * 8];
      short8 bk1 = *(const short8*)&Ks[j * 16 + l16][32 + quad * 8];
      s[j] = __builtin_amdgcn_mfma_f32_16x16x32_bf16(aq0, bk0, s[j], 0, 0, 0);
      s[j] = __builtin_amdgcn_mfma_f32_16x16x32_bf16(aq1, bk1, s[j], 0, 0, 0);
    }

    float mx[4], al[4], ts[4];
    #pragma unroll
    for (int r = 0; r < 4; ++r)
      mx[r] = fmaxf(fmaxf(s[0][r], s[1][r]), fmaxf(s[2][r], s[3][r]));
    #pragma unroll
    for (int mask = 1; mask < 16; mask <<= 1)
      #pragma unroll
      for (int r = 0; r < 4; ++r)
        mx[r] = fmaxf(mx[r], __shfl_xor(mx[r], mask));
    #pragma unroll
    for (int r = 0; r < 4; ++r) {
      float mnew = fmaxf(m_run[r], mx[r]);
      al[r] = __expf(m_run[r] - mnew);
      m_run[r] = mnew;
      ts[r] = 0.f;
    }
    #pragma unroll
    for (int j = 0; j < 4; ++j) {
      bool valid = (j0 + j * 16 + l16) < NPATCH;
      #pragma unroll
      for (int r = 0; r < 4; ++r) {
        float p = valid ? __expf(s[j][r] - m_run[r]) : 0.f;
        ts[r] += p;
        Ps[wave][quad * 4 + r][j * 16 + l16] = f2bf(p);
      }
    }
    #pragma unroll
    for (int mask = 1; mask < 16; mask <<= 1)
      #pragma unroll
      for (int r = 0; r < 4; ++r)
        ts[r] += __shfl_xor(ts[r], mask);
    #pragma unroll
    for (int r = 0; r < 4; ++r) l_run[r] = l_run[r] * al[r] + ts[r];
    #pragma unroll
    for (int j2 = 0; j2 < 4; ++j2)
      #pragma unroll
      for (int r = 0; r < 4; ++r)
        accO[j2][r] *= al[r];

    short8 pa0 = *(const short8*)&Ps[wave][l16][quad * 8];
    short8 pa1 = *(const short8*)&Ps[wave][l16][32 + quad * 8];
    #pragma unroll
    for (int j2 = 0; j2 < 4; ++j2) {
      short8 v0 = *(const short8*)&Vt[j2 * 16 + l16][quad * 8];
      short8 v1 = *(const short8*)&Vt[j2 * 16 + l16][32 + quad * 8];
      accO[j2] = __builtin_amdgcn_mfma_f32_16x16x32_bf16(pa0, v0, accO[j2], 0, 0, 0);
      accO[j2] = __builtin_amdgcn_mfma_f32_16x16x32_bf16(pa1, v1, accO[j2], 0, 0, 0);
    }
    __syncthreads();
  }

  #pragma unroll
  for (int r = 0; r < 4; ++r) {
    int qi = qt0 + wave * 16 + quad * 4 + r;
    if (qi < NPATCH) {
      float inv = 1.f / l_run[r];
      size_t off = (size_t)(b * NPATCH + qi) * DIM + h * HD + l16;
      #pragma unroll
      for (int j2 = 0; j2 < 4; ++j2)
        o[off + j2 * 16] = f2bf(accO[j2][r] * inv);
    }
  }
}

// ---------------------------------------------------------------------------
extern "C" void kernel_launch(void* const* d_in, const int* in_sizes, int n_in,
                              void* d_out, int out_size, void* d_ws, size_t ws_size,
                              hipStream_t stream) {
  const float* x      = (const float*)d_in[0];
  const float* W_emb  = (const float*)d_in[1];
  const float* b_emb  = (const float*)d_in[2];
  const float* ln1_g  = (const float*)d_in[3];
  const float* ln1_b  = (const float*)d_in[4];
  const float* W_qkv  = (const float*)d_in[5];
  const float* b_qkv  = (const float*)d_in[6];
  const float* W_proj = (const float*)d_in[7];
  const float* b_proj = (const float*)d_in[8];
  const float* ln2_g  = (const float*)d_in[9];
  const float* ln2_b  = (const float*)d_in[10];
  const float* W_mlp1 = (const float*)d_in[11];
  const float* b_mlp1 = (const float*)d_in[12];
  const float* W_mlp2 = (const float*)d_in[13];
  const float* b_mlp2 = (const float*)d_in[14];
  const float* lnf_g  = (const float*)d_in[15];
  const float* lnf_b  = (const float*)d_in[16];
  float* out = (float*)d_out;

  // workspace: h 8.4M | qkvb/midbf 16.8M | ybf/obf 4.2M | Wt 25.2M |
  //            rtab 0.26M | Pm 1.05M | Wembt 0.13M  -> ~56 MB
  float* h              = (float*)d_ws;
  unsigned short* qkvb  = (unsigned short*)(h + (size_t)M_ROWS * DIM);
  unsigned short* midbf = qkvb;   // alias: qkvb dead after attn
  unsigned short* ybf   = qkvb + (size_t)M_ROWS * MLP_HID;
  unsigned short* obf   = ybf;    // alias: ybf dead after its GEMM
  unsigned short* wqkv_t  = ybf + (size_t)M_ROWS * DIM;
  unsigned short* wproj_t = wqkv_t  + (size_t)NLAYERS * DIM * 3 * DIM;
  unsigned short* wmlp1_t = wproj_t + (size_t)NLAYERS * DIM * DIM;
  unsigned short* wmlp2_t = wmlp1_t + (size_t)NLAYERS * DIM * MLP_HID;
  float2* rtab = (float2*)(wmlp2_t + (size_t)NLAYERS * MLP_HID * DIM);
  unsigned short* Pm    = (unsigned short*)(rtab + (size_t)NPATCH * 32);
  unsigned short* Wembt = Pm + (size_t)M_ROWS * KEMB;

  wcvt_kernel<<<dim3(3 * DIM / 32, DIM / 32, NLAYERS), 256, 0, stream>>>(W_qkv,  wqkv_t,  DIM, 3 * DIM);
  wcvt_kernel<<<dim3(DIM / 32, DIM / 32, NLAYERS),     256, 0, stream>>>(W_proj, wproj_t, DIM, DIM);
  wcvt_kernel<<<dim3(MLP_HID / 32, DIM / 32, NLAYERS), 256, 0, stream>>>(W_mlp1, wmlp1_t, DIM, MLP_HID);
  wcvt_kernel<<<dim3(DIM / 32, MLP_HID / 32, NLAYERS), 256, 0, stream>>>(W_mlp2, wmlp2_t, MLP_HID, DIM);
  rope_tab_kernel<<<(NPATCH * 32 + 255) / 256, 256, 0, stream>>>(rtab);
  patch_kernel<<<(M_ROWS * KEMB + 255) / 256, 256, 0, stream>>>(x, Pm);
  wemb_cvt_kernel<<<(DIM * KEMB + 255) / 256, 256, 0, stream>>>(W_emb, Wembt);

  const int MT32  = (M_ROWS + 31) / 32;    // 128
  const int MT64  = (M_ROWS + 63) / 64;    // 64
  const int LNG = (M_ROWS + 3) / 4;        // 1023

  // embed as MFMA GEMM: out & h = Pm @ Wembt^T + b_emb
  mfma_gemm<64, 5><<<dim3(DIM / 128, MT64), 256, 0, stream>>>(
      Pm, Wembt, b_emb, nullptr, out, h, nullptr, nullptr, M_ROWS, DIM, KEMB);

  for (int L = 0; L < NLAYERS; ++L) {
    ln_kernel<true><<<LNG, 256, 0, stream>>>(h, ln1_g + L * DIM, ln1_b + L * DIM, ybf, M_ROWS);
    // qkv with fused RoPE (768 blocks)
    mfma_gemm<64, 6><<<dim3(3 * DIM / 128, MT64), 256, 0, stream>>>(
        ybf, wqkv_t + (size_t)L * DIM * 3 * DIM, b_qkv + L * 3 * DIM,
        nullptr, nullptr, nullptr, qkvb, rtab, M_ROWS, 3 * DIM, DIM);
    attn_kernel<<<dim3((NPATCH + 63) / 64, NH, B_SZ), 256, 0, stream>>>(qkvb, obf);
    // proj: h += o @ Wp + bias  (512 blocks, TM=32)
    mfma_gemm<32, 1><<<dim3(DIM / 128, MT32), 256, 0, stream>>>(
        obf, wproj_t + (size_t)L * DIM * DIM, b_proj + L * DIM,
        h, h, nullptr, nullptr, nullptr, M_ROWS, DIM, DIM);
    ln_kernel<true><<<LNG, 256, 0, stream>>>(h, ln2_g + L * DIM, ln2_b + L * DIM, ybf, M_ROWS);
    // mlp1 (1024 blocks, TM=64)
    mfma_gemm<64, 2><<<dim3(MLP_HID / 128, MT64), 256, 0, stream>>>(
        ybf, wmlp1_t + (size_t)L * DIM * MLP_HID, b_mlp1 + L * MLP_HID,
        nullptr, nullptr, nullptr, midbf, nullptr, M_ROWS, MLP_HID, DIM);
    // mlp2: h += mid @ Wm2 + bias  (512 blocks, TM=32)
    mfma_gemm<32, 1><<<dim3(DIM / 128, MT32), 256, 0, stream>>>(
        midbf, wmlp2_t + (size_t)L * MLP_HID * DIM, b_mlp2 + L * DIM,
        h, h, nullptr, nullptr, nullptr, M_ROWS, DIM, MLP_HID);
  }

  ln_kernel<false><<<LNG, 256, 0, stream>>>(h, lnf_g, lnf_b, out + (size_t)M_ROWS * DIM, M_ROWS);
}

// Round 10
// 696.331 us; speedup vs baseline: 2.0324x; 2.0324x over previous
//
#include <hip/hip_runtime.h>
#include <hip/hip_bf16.h>
#include <math.h>

#define B_SZ 4
#define T_LEN 8192
#define C_IN 7
#define NPATCH 1023
#define DIM 512
#define NH 8
#define HD 64
#define NLAYERS 4
#define MLP_HID 2048
#define M_ROWS (B_SZ * NPATCH)   // 4092
#define KEMB 128                 // padded patch length (112 real + 16 zero)
#define LN_EPS 1e-5f

typedef __attribute__((ext_vector_type(8))) short short8;
typedef __attribute__((ext_vector_type(4))) float float4v;

static __device__ __forceinline__ unsigned short f2bf(float f) {
  __hip_bfloat16 h = __float2bfloat16(f);
  return *reinterpret_cast<unsigned short*>(&h);
}
static __device__ __forceinline__ float bf2f(unsigned short u) {
  return __uint_as_float(((unsigned)u) << 16);
}

// ---------------------------------------------------------------------------
// Patch gather: Pm[row][c*16+p] = bf16(x[b, i*8+p, c]); cols 112..127 = 0.
// ---------------------------------------------------------------------------
__global__ __launch_bounds__(256) void patch_kernel(
    const float* __restrict__ x, unsigned short* __restrict__ Pm) {
  int idx = blockIdx.x * 256 + threadIdx.x;
  if (idx >= M_ROWS * KEMB) return;
  int row = idx >> 7, c = idx & 127;
  float v = 0.f;
  if (c < 112) {
    int b = row / NPATCH, i = row - b * NPATCH;
    int ci = c >> 4, p = c & 15;
    v = x[((size_t)b * T_LEN + (size_t)i * 8 + p) * C_IN + ci];
  }
  Pm[idx] = f2bf(v);
}

// ---------------------------------------------------------------------------
// W_emb convert: Wt[n][k] = bf16(W_emb[k][n]) for k<112, 0 for k in [112,128).
// ---------------------------------------------------------------------------
__global__ __launch_bounds__(256) void wemb_cvt_kernel(
    const float* __restrict__ W, unsigned short* __restrict__ Wt) {
  int idx = blockIdx.x * 256 + threadIdx.x;
  if (idx >= DIM * KEMB) return;
  int n = idx >> 7, k = idx & 127;
  float v = (k < 112) ? W[(size_t)k * DIM + n] : 0.f;
  Wt[idx] = f2bf(v);
}

// ---------------------------------------------------------------------------
// LayerNorm, 4 rows/block. BF: bf16 vs fp32 out.
// ---------------------------------------------------------------------------
template <bool BF>
__global__ __launch_bounds__(256) void ln_kernel(
    const float* __restrict__ in, const float* __restrict__ g,
    const float* __restrict__ bb, void* __restrict__ outv, int M) {
  int row = blockIdx.x * 4 + (threadIdx.x >> 6);
  if (row >= M) return;
  int lane = threadIdx.x & 63;
  const float* xr = in + (size_t)row * DIM;
  float v[8];
  float s = 0.f;
  #pragma unroll
  for (int k = 0; k < 8; ++k) { v[k] = xr[lane + 64 * k]; s += v[k]; }
  #pragma unroll
  for (int off = 32; off; off >>= 1) s += __shfl_down(s, off);
  s = __shfl(s, 0);
  float mu = s * (1.f / DIM);
  float q = 0.f;
  #pragma unroll
  for (int k = 0; k < 8; ++k) { float d = v[k] - mu; q = fmaf(d, d, q); }
  #pragma unroll
  for (int off = 32; off; off >>= 1) q += __shfl_down(q, off);
  q = __shfl(q, 0);
  float rstd = rsqrtf(q * (1.f / DIM) + LN_EPS);
  #pragma unroll
  for (int k = 0; k < 8; ++k) {
    int d = lane + 64 * k;
    float r = (v[k] - mu) * rstd * g[d] + bb[d];
    if (BF)
      ((unsigned short*)outv)[(size_t)row * DIM + d] = f2bf(r);
    else
      ((float*)outv)[(size_t)row * DIM + d] = r;
  }
}

// ---------------------------------------------------------------------------
// Weight convert + transpose: W[K][N] fp32 -> Wt[N][K] bf16 (per layer z).
// ---------------------------------------------------------------------------
__global__ __launch_bounds__(256) void wcvt_kernel(
    const float* __restrict__ W, unsigned short* __restrict__ Wt, int K, int N) {
  __shared__ float tile[32][33];
  int n0 = blockIdx.x * 32, k0 = blockIdx.y * 32, L = blockIdx.z;
  const float* Ws = W + (size_t)L * K * N;
  unsigned short* Wd = Wt + (size_t)L * K * N;
  int tx = threadIdx.x & 31, ty = threadIdx.x >> 5;
  #pragma unroll
  for (int i = 0; i < 4; ++i)
    tile[ty + i * 8][tx] = Ws[(size_t)(k0 + ty + i * 8) * N + n0 + tx];
  __syncthreads();
  #pragma unroll
  for (int i = 0; i < 4; ++i)
    Wd[(size_t)(n0 + ty + i * 8) * K + k0 + tx] = f2bf(tile[tx][ty + i * 8]);
}

// ---------------------------------------------------------------------------
// RoPE cos/sin table: tab[i*32+j] = (cos, sin) of i * 10000^(-j/32).
// ---------------------------------------------------------------------------
__global__ __launch_bounds__(256) void rope_tab_kernel(float2* __restrict__ tab) {
  int idx = blockIdx.x * 256 + threadIdx.x;
  if (idx >= NPATCH * 32) return;
  int i = idx >> 5, j = idx & 31;
  float inv = powf(10000.0f, -(float)j * (1.0f / 32.0f));
  float sn, cs;
  sincosf((float)i * inv, &sn, &cs);
  tab[idx] = make_float2(cs, sn);
}

// ---------------------------------------------------------------------------
// bf16 MFMA GEMM, TM x TN tile, BK=32, 4 waves (2x2), double-buffered LDS,
// ONE barrier per K-iter: write LDS[buf] -> prefetch next tile to regs ->
// __syncthreads -> MFMA from LDS[buf]. No trailing barrier (next iter writes
// the other buffer; race-free). Prefetch loads fly across the MFMA block.
// EPI: 1 = bias + res -> fp32 (res==Cf ok: h += ...);
//      2 = bias + GELU -> bf16; 3 = bias -> bf16;
//      5 = bias -> fp32 to BOTH Cf and Cf2 (embed);
//      6 = bias + RoPE (q scaled 1/8) -> bf16 (qkv; needs TN=128).
// ---------------------------------------------------------------------------
template <int TM, int TN, int EPI>
__global__ __launch_bounds__(256) void mfma_gemm(
    const unsigned short* __restrict__ A, const unsigned short* __restrict__ Bt,
    const float* __restrict__ bias, const float* __restrict__ res,
    float* __restrict__ Cf, float* __restrict__ Cf2,
    unsigned short* __restrict__ Cb, const float2* __restrict__ rtab,
    int M, int N, int K) {
  constexpr int WM = TM / 2, WN = TN / 2;
  constexpr int NI = WM / 16, NJ = WN / 16;
  constexpr int ACH = TM * 4;               // A uint4 chunks per K-tile
  constexpr int TCH = (TM + TN) * 4;        // total chunks
  constexpr int CH = TCH / 256;             // chunks per thread
  __shared__ __align__(16) unsigned short As[2][TM][40];
  __shared__ __align__(16) unsigned short Bs[2][TN][40];
  const int bm = blockIdx.y * TM;
  const int bn = blockIdx.x * TN;
  const int tid = threadIdx.x;
  const int lane = tid & 63, wave = tid >> 6;
  const int quad = lane >> 4, l16 = lane & 15;
  const int wm = (wave & 1) * WM;
  const int wn = (wave >> 1) * WN;

  float4v acc[NI][NJ];
  #pragma unroll
  for (int i = 0; i < NI; ++i)
    #pragma unroll
    for (int j = 0; j < NJ; ++j)
      acc[i][j] = (float4v){0.f, 0.f, 0.f, 0.f};

  uint4 pr[CH];
  auto load_regs = [&](int kk) {
    #pragma unroll
    for (int it = 0; it < CH; ++it) {
      int c = tid + it * 256;
      if (c < ACH) {
        int row = c >> 2, ch = (c & 3) * 8;
        int gm = bm + row;
        pr[it] = make_uint4(0u, 0u, 0u, 0u);
        if (gm < M) pr[it] = *(const uint4*)(A + (size_t)gm * K + kk + ch);
      } else {
        int c2 = c - ACH;
        int row = c2 >> 2, ch = (c2 & 3) * 8;
        pr[it] = *(const uint4*)(Bt + (size_t)(bn + row) * K + kk + ch);
      }
    }
  };

  load_regs(0);
  int buf = 0;
  for (int k0 = 0; k0 < K; k0 += 32, buf ^= 1) {
    #pragma unroll
    for (int it = 0; it < CH; ++it) {
      int c = tid + it * 256;
      if (c < ACH)
        *(uint4*)&As[buf][c >> 2][(c & 3) * 8] = pr[it];
      else {
        int c2 = c - ACH;
        *(uint4*)&Bs[buf][c2 >> 2][(c2 & 3) * 8] = pr[it];
      }
    }
    if (k0 + 32 < K) load_regs(k0 + 32);   // prefetch; flies across MFMA block
    __syncthreads();
    short8 af[NI], bfr[NJ];
    #pragma unroll
    for (int i = 0; i < NI; ++i)
      af[i] = *(const short8*)&As[buf][wm + i * 16 + l16][quad * 8];
    #pragma unroll
    for (int j = 0; j < NJ; ++j)
      bfr[j] = *(const short8*)&Bs[buf][wn + j * 16 + l16][quad * 8];
    #pragma unroll
    for (int i = 0; i < NI; ++i)
      #pragma unroll
      for (int j = 0; j < NJ; ++j)
        acc[i][j] = __builtin_amdgcn_mfma_f32_16x16x32_bf16(
            af[i], bfr[j], acc[i][j], 0, 0, 0);
    // no trailing barrier: next iter writes the other LDS buffer
  }

  if (EPI == 6) {
    const int sec = (bn + wn) >> 9;   // 0=q, 1=k, 2=v (wave-uniform; TN=128)
    #pragma unroll
    for (int i = 0; i < NI; ++i) {
      int gm0 = bm + wm + i * 16 + quad * 4;
      #pragma unroll
      for (int r = 0; r < 4; ++r) {
        int gm = gm0 + r;
        if (gm >= M) continue;
        size_t rowoff = (size_t)gm * N;
        if (sec < 2) {
          int ip = gm; if (ip >= 2046) ip -= 2046; if (ip >= 1023) ip -= 1023;
          float sc = (sec == 0) ? 0.125f : 1.f;
          #pragma unroll
          for (int j = 0; j < 2; ++j) {
            int gn = bn + wn + j * 16 + l16;
            float v0 = acc[i][j][r] + bias[gn];
            float v1 = acc[i][j + 2][r] + bias[gn + 32];
            float2 t = rtab[ip * 32 + j * 16 + l16];
            Cb[rowoff + gn]      = f2bf((v0 * t.x - v1 * t.y) * sc);
            Cb[rowoff + gn + 32] = f2bf((v1 * t.x + v0 * t.y) * sc);
          }
        } else {
          #pragma unroll
          for (int j = 0; j < 4; ++j) {
            int gn = bn + wn + j * 16 + l16;
            Cb[rowoff + gn] = f2bf(acc[i][j][r] + bias[gn]);
          }
        }
      }
    }
    return;
  }

  #pragma unroll
  for (int j = 0; j < NJ; ++j) {
    int gn = bn + wn + j * 16 + l16;
    float bv = bias[gn];
    #pragma unroll
    for (int i = 0; i < NI; ++i) {
      int gm0 = bm + wm + i * 16 + quad * 4;
      #pragma unroll
      for (int r = 0; r < 4; ++r) {
        int gm = gm0 + r;
        if (gm < M) {
          float v = acc[i][j][r] + bv;
          size_t off = (size_t)gm * N + gn;
          if (EPI == 1) {
            Cf[off] = v + res[off];
          } else if (EPI == 2) {
            Cb[off] = f2bf(0.5f * v * (1.f + erff(v * 0.70710678118f)));
          } else if (EPI == 3) {
            Cb[off] = f2bf(v);
          } else {
            Cf[off] = v;
            Cf2[off] = v;
          }
        }
      }
    }
  }
}

// ---------------------------------------------------------------------------
// MFMA flash attention with depth-1 K/V register prefetch (R8, passed).
// ---------------------------------------------------------------------------
#define APITCH 72

__global__ __launch_bounds__(256) void attn_kernel(
    const unsigned short* __restrict__ qkvb, unsigned short* __restrict__ o) {
  const int qt0 = blockIdx.x * 64;
  const int h = blockIdx.y;
  const int b = blockIdx.z;
  const int tid = threadIdx.x;
  const int lane = tid & 63, wave = tid >> 6;
  const int quad = lane >> 4, l16 = lane & 15;

  __shared__ __align__(16) unsigned short Qs[64][APITCH];
  __shared__ __align__(16) unsigned short Ks[64][APITCH];
  __shared__ __align__(16) unsigned short Vt[HD][APITCH];
  __shared__ __align__(16) unsigned short Ps[4][16][APITCH];

  const int sr = tid >> 2;
  const int sc0 = (tid & 3) * 16;

  {
    int qi = qt0 + sr;
    uint4 a = make_uint4(0u, 0u, 0u, 0u), b2 = a;
    if (qi < NPATCH) {
      const uint4* src = (const uint4*)(qkvb + (size_t)(b * NPATCH + qi) * (3 * DIM) + h * HD + sc0);
      a = src[0]; b2 = src[1];
    }
    *(uint4*)&Qs[sr][sc0] = a;
    *(uint4*)&Qs[sr][sc0 + 8] = b2;
  }

  uint4 pk0, pk1, pv0, pv1;
  auto load_kv = [&](int j0) {
    int j = j0 + sr;
    pk0 = pk1 = pv0 = pv1 = make_uint4(0u, 0u, 0u, 0u);
    if (j < NPATCH) {
      const unsigned short* baseb = qkvb + (size_t)(b * NPATCH + j) * (3 * DIM) + h * HD;
      pk0 = *(const uint4*)(baseb + DIM + sc0);
      pk1 = *(const uint4*)(baseb + DIM + sc0 + 8);
      pv0 = *(const uint4*)(baseb + 2 * DIM + sc0);
      pv1 = *(const uint4*)(baseb + 2 * DIM + sc0 + 8);
    }
  };
  load_kv(0);
  __syncthreads();

  short8 aq0 = *(const short8*)&Qs[wave * 16 + l16][quad * 8];
  short8 aq1 = *(const short8*)&Qs[wave * 16 + l16][32 + quad * 8];

  float4v accO[4];
  #pragma unroll
  for (int j2 = 0; j2 < 4; ++j2) accO[j2] = (float4v){0.f, 0.f, 0.f, 0.f};
  float m_run[4] = {-1e30f, -1e30f, -1e30f, -1e30f};
  float l_run[4] = {0.f, 0.f, 0.f, 0.f};

  for (int j0 = 0; j0 < NPATCH; j0 += 64) {
    {
      *(uint4*)&Ks[sr][sc0] = pk0;
      *(uint4*)&Ks[sr][sc0 + 8] = pk1;
      unsigned short vs[16];
      *(uint4*)&vs[0] = pv0;
      *(uint4*)&vs[8] = pv1;
      #pragma unroll
      for (int u = 0; u < 16; ++u) Vt[sc0 + u][sr] = vs[u];
    }
    __syncthreads();
    if (j0 + 64 < NPATCH) load_kv(j0 + 64);

    float4v s[4];
    #pragma unroll
    for (int j = 0; j < 4; ++j) {
      s[j] = (float4v){0.f, 0.f, 0.f, 0.f};
      short8 bk0 = *(const short8*)&Ks[j * 16 + l16][quad * 8];
      short8 bk1 = *(const short8*)&Ks[j * 16 + l16][32 + quad * 8];
      s[j] = __builtin_amdgcn_mfma_f32_16x16x32_bf16(aq0, bk0, s[j], 0, 0, 0);
      s[j] = __builtin_amdgcn_mfma_f32_16x16x32_bf16(aq1, bk1, s[j], 0, 0, 0);
    }

    float mx[4], al[4], ts[4];
    #pragma unroll
    for (int r = 0; r < 4; ++r)
      mx[r] = fmaxf(fmaxf(s[0][r], s[1][r]), fmaxf(s[2][r], s[3][r]));
    #pragma unroll
    for (int mask = 1; mask < 16; mask <<= 1)
      #pragma unroll
      for (int r = 0; r < 4; ++r)
        mx[r] = fmaxf(mx[r], __shfl_xor(mx[r], mask));
    #pragma unroll
    for (int r = 0; r < 4; ++r) {
      float mnew = fmaxf(m_run[r], mx[r]);
      al[r] = __expf(m_run[r] - mnew);
      m_run[r] = mnew;
      ts[r] = 0.f;
    }
    #pragma unroll
    for (int j = 0; j < 4; ++j) {
      bool valid = (j0 + j * 16 + l16) < NPATCH;
      #pragma unroll
      for (int r = 0; r < 4; ++r) {
        float p = valid ? __expf(s[j][r] - m_run[r]) : 0.f;
        ts[r] += p;
        Ps[wave][quad * 4 + r][j * 16 + l16] = f2bf(p);
      }
    }
    #pragma unroll
    for (int mask = 1; mask < 16; mask <<= 1)
      #pragma unroll
      for (int r = 0; r < 4; ++r)
        ts[r] += __shfl_xor(ts[r], mask);
    #pragma unroll
    for (int r = 0; r < 4; ++r) l_run[r] = l_run[r] * al[r] + ts[r];
    #pragma unroll
    for (int j2 = 0; j2 < 4; ++j2)
      #pragma unroll
      for (int r = 0; r < 4; ++r)
        accO[j2][r] *= al[r];

    short8 pa0 = *(const short8*)&Ps[wave][l16][quad * 8];
    short8 pa1 = *(const short8*)&Ps[wave][l16][32 + quad * 8];
    #pragma unroll
    for (int j2 = 0; j2 < 4; ++j2) {
      short8 v0 = *(const short8*)&Vt[j2 * 16 + l16][quad * 8];
      short8 v1 = *(const short8*)&Vt[j2 * 16 + l16][32 + quad * 8];
      accO[j2] = __builtin_amdgcn_mfma_f32_16x16x32_bf16(pa0, v0, accO[j2], 0, 0, 0);
      accO[j2] = __builtin_amdgcn_mfma_f32_16x16x32_bf16(pa1, v1, accO[j2], 0, 0, 0);
    }
    __syncthreads();
  }

  #pragma unroll
  for (int r = 0; r < 4; ++r) {
    int qi = qt0 + wave * 16 + quad * 4 + r;
    if (qi < NPATCH) {
      float inv = 1.f / l_run[r];
      size_t off = (size_t)(b * NPATCH + qi) * DIM + h * HD + l16;
      #pragma unroll
      for (int j2 = 0; j2 < 4; ++j2)
        o[off + j2 * 16] = f2bf(accO[j2][r] * inv);
    }
  }
}

// ---------------------------------------------------------------------------
extern "C" void kernel_launch(void* const* d_in, const int* in_sizes, int n_in,
                              void* d_out, int out_size, void* d_ws, size_t ws_size,
                              hipStream_t stream) {
  const float* x      = (const float*)d_in[0];
  const float* W_emb  = (const float*)d_in[1];
  const float* b_emb  = (const float*)d_in[2];
  const float* ln1_g  = (const float*)d_in[3];
  const float* ln1_b  = (const float*)d_in[4];
  const float* W_qkv  = (const float*)d_in[5];
  const float* b_qkv  = (const float*)d_in[6];
  const float* W_proj = (const float*)d_in[7];
  const float* b_proj = (const float*)d_in[8];
  const float* ln2_g  = (const float*)d_in[9];
  const float* ln2_b  = (const float*)d_in[10];
  const float* W_mlp1 = (const float*)d_in[11];
  const float* b_mlp1 = (const float*)d_in[12];
  const float* W_mlp2 = (const float*)d_in[13];
  const float* b_mlp2 = (const float*)d_in[14];
  const float* lnf_g  = (const float*)d_in[15];
  const float* lnf_b  = (const float*)d_in[16];
  float* out = (float*)d_out;

  float* h              = (float*)d_ws;
  unsigned short* qkvb  = (unsigned short*)(h + (size_t)M_ROWS * DIM);
  unsigned short* midbf = qkvb;   // alias: qkvb dead after attn
  unsigned short* ybf   = qkvb + (size_t)M_ROWS * MLP_HID;
  unsigned short* obf   = ybf;    // alias: ybf dead after its GEMM
  unsigned short* wqkv_t  = ybf + (size_t)M_ROWS * DIM;
  unsigned short* wproj_t = wqkv_t  + (size_t)NLAYERS * DIM * 3 * DIM;
  unsigned short* wmlp1_t = wproj_t + (size_t)NLAYERS * DIM * DIM;
  unsigned short* wmlp2_t = wmlp1_t + (size_t)NLAYERS * DIM * MLP_HID;
  float2* rtab = (float2*)(wmlp2_t + (size_t)NLAYERS * MLP_HID * DIM);
  unsigned short* Pm    = (unsigned short*)(rtab + (size_t)NPATCH * 32);
  unsigned short* Wembt = Pm + (size_t)M_ROWS * KEMB;

  wcvt_kernel<<<dim3(3 * DIM / 32, DIM / 32, NLAYERS), 256, 0, stream>>>(W_qkv,  wqkv_t,  DIM, 3 * DIM);
  wcvt_kernel<<<dim3(DIM / 32, DIM / 32, NLAYERS),     256, 0, stream>>>(W_proj, wproj_t, DIM, DIM);
  wcvt_kernel<<<dim3(MLP_HID / 32, DIM / 32, NLAYERS), 256, 0, stream>>>(W_mlp1, wmlp1_t, DIM, MLP_HID);
  wcvt_kernel<<<dim3(DIM / 32, MLP_HID / 32, NLAYERS), 256, 0, stream>>>(W_mlp2, wmlp2_t, MLP_HID, DIM);
  rope_tab_kernel<<<(NPATCH * 32 + 255) / 256, 256, 0, stream>>>(rtab);
  patch_kernel<<<(M_ROWS * KEMB + 255) / 256, 256, 0, stream>>>(x, Pm);
  wemb_cvt_kernel<<<(DIM * KEMB + 255) / 256, 256, 0, stream>>>(W_emb, Wembt);

  const int MT64 = (M_ROWS + 63) / 64;   // 64
  const int LNG = (M_ROWS + 3) / 4;      // 1023

  // embed: out & h = Pm @ Wembt^T + b_emb  (TN=64: 512 blocks)
  mfma_gemm<64, 64, 5><<<dim3(DIM / 64, MT64), 256, 0, stream>>>(
      Pm, Wembt, b_emb, nullptr, out, h, nullptr, nullptr, M_ROWS, DIM, KEMB);

  for (int L = 0; L < NLAYERS; ++L) {
    ln_kernel<true><<<LNG, 256, 0, stream>>>(h, ln1_g + L * DIM, ln1_b + L * DIM, ybf, M_ROWS);
    // qkv with fused RoPE (TN=128: 768 blocks)
    mfma_gemm<64, 128, 6><<<dim3(3 * DIM / 128, MT64), 256, 0, stream>>>(
        ybf, wqkv_t + (size_t)L * DIM * 3 * DIM, b_qkv + L * 3 * DIM,
        nullptr, nullptr, nullptr, qkvb, rtab, M_ROWS, 3 * DIM, DIM);
    attn_kernel<<<dim3((NPATCH + 63) / 64, NH, B_SZ), 256, 0, stream>>>(qkvb, obf);
    // proj: h += o @ Wp + bias  (TN=64: 512 blocks)
    mfma_gemm<64, 64, 1><<<dim3(DIM / 64, MT64), 256, 0, stream>>>(
        obf, wproj_t + (size_t)L * DIM * DIM, b_proj + L * DIM,
        h, h, nullptr, nullptr, nullptr, M_ROWS, DIM, DIM);
    ln_kernel<true><<<LNG, 256, 0, stream>>>(h, ln2_g + L * DIM, ln2_b + L * DIM, ybf, M_ROWS);
    // mlp1 (TN=128: 1024 blocks)
    mfma_gemm<64, 128, 2><<<dim3(MLP_HID / 128, MT64), 256, 0, stream>>>(
        ybf, wmlp1_t + (size_t)L * DIM * MLP_HID, b_mlp1 + L * MLP_HID,
        nullptr, nullptr, nullptr, midbf, nullptr, M_ROWS, MLP_HID, DIM);
    // mlp2: h += mid @ Wm2 + bias  (TN=64: 512 blocks)
    mfma_gemm<64, 64, 1><<<dim3(DIM / 64, MT64), 256, 0, stream>>>(
        midbf, wmlp2_t + (size_t)L * MLP_HID * DIM, b_mlp2 + L * DIM,
        h, h, nullptr, nullptr, nullptr, M_ROWS, DIM, MLP_HID);
  }

  ln_kernel<false><<<LNG, 256, 0, stream>>>(h, lnf_g, lnf_b, out + (size_t)M_ROWS * DIM, M_ROWS);
}